// Round 1
// baseline (2226.320 us; speedup 1.0000x reference)
//
#include <hip/hip_runtime.h>

// ---------------------------------------------------------------------------
// Faster-RCNN head pipeline, fp32 throughout (scores feed exact top-k + NMS:
// ordering-sensitive, so no low-precision shortcuts on the conv path).
//
// Workspace layout (bytes):
//   0          : h   [512][6400]           (13,107,200)   -- dead after k_rpn
//   0          : ft  [6400][1024]          (26,214,400)   -- overlays h, written after k_rpn
//   26,214,400 : clsL  [18][6400]          (460,800)
//   26,675,200 : bboxL [36][6400]          (921,600)
//   27,596,800 : boxes [57600] float4      (921,600)
//   28,518,400 : keys  [57600] u64         (460,800)
//   28,979,200 : hist  [65536] u32         (262,144)      -- memset each launch
//   29,241,344 : meta  [64] u32            (256)          -- memset each launch
//   29,241,600 : rnk   [57600] i32         (230,400)      -- memset each launch
//   29,472,000 : cand  [57600] i32         (230,400)
//   29,702,400 : btop  [6000] float4       (96,000)
//   29,798,400 : mask  [6000][94] u64      (4,512,000)
//   34,310,400 : roib  [300] float4        (4,800)
//   34,315,200 : vec   [300][1024]         (1,228,800)
//   35,544,000 : hidden[300][2048]         (2,457,600)    -- end 38,001,600
// ---------------------------------------------------------------------------

#define OFF_CLS   26214400u
#define OFF_BBOX  26675200u
#define OFF_BOXES 27596800u
#define OFF_KEYS  28518400u
#define OFF_HIST  28979200u
#define OFF_META  29241344u
#define OFF_RNK   29241600u
#define OFF_CAND  29472000u
#define OFF_BTOP  29702400u
#define OFF_MASK  29798400u
#define OFF_ROIB  34310400u
#define OFF_VEC   34315200u
#define OFF_HID   35544000u

// ---------------------------------------------------------------------------
// Kernel 1: 3x3 conv 1024->512 over 64x100, SAME pad, +bias, ReLU.
// grid (25,16), block (64,4). Each thread: 4 consecutive x-pixels x 8 oc.
// Weights staged per-32-ic chunk in LDS ([ic*9+tap]*36 + ocl, stride 36 for
// b128 alignment). Inner: 9 guarded input loads + 18 LDS b128 + 288 FMA / ic.
// ---------------------------------------------------------------------------
__global__ __launch_bounds__(256) void k_conv(const float* __restrict__ in,
                                              const float* __restrict__ wgt,
                                              const float* __restrict__ bias,
                                              float* __restrict__ out) {
  const int tx = threadIdx.x;            // 0..63 pixel-group lane
  const int ty = threadIdx.y;            // 0..3 oc sub-group (wave-uniform)
  const int pg = blockIdx.x * 64 + tx;   // 0..1599
  const int p0 = pg * 4;                 // base pixel (4 consecutive, same row)
  const int y  = p0 / 100;
  const int x0 = p0 % 100;               // multiple of 4 -> float4 aligned
  const int ocb = blockIdx.y * 32;
  const int tid = ty * 64 + tx;

  __shared__ float sw[32 * 9 * 36];      // 41,472 B

  float acc[8][4];
#pragma unroll
  for (int j = 0; j < 8; ++j)
#pragma unroll
    for (int q = 0; q < 4; ++q) acc[j][q] = 0.f;

  for (int icb = 0; icb < 1024; icb += 32) {
    __syncthreads();
    // stage weights: per ocl, 288 contiguous floats (32 ic x 9 taps)
    for (int k = tid; k < 32 * 288; k += 256) {
      int ocl = k / 288, r = k % 288;
      sw[r * 36 + ocl] = wgt[(size_t)(ocb + ocl) * 9216 + icb * 9 + r];
    }
    __syncthreads();

    for (int icl = 0; icl < 32; ++icl) {
      const float* pin = in + (size_t)(icb + icl) * 6400;
      float r[3][6];
#pragma unroll
      for (int dy = 0; dy < 3; ++dy) {
        int yy = y + dy - 1;
        bool vr = (yy >= 0) && (yy < 64);
        const float* prow = pin + yy * 100;
        float4 m = vr ? *(const float4*)(prow + x0) : make_float4(0.f, 0.f, 0.f, 0.f);
        r[dy][1] = m.x; r[dy][2] = m.y; r[dy][3] = m.z; r[dy][4] = m.w;
        r[dy][0] = (vr && x0 > 0)       ? prow[x0 - 1] : 0.f;
        r[dy][5] = (vr && x0 + 4 < 100) ? prow[x0 + 4] : 0.f;
      }
#pragma unroll
      for (int tap = 0; tap < 9; ++tap) {
        const int dy = tap / 3, kx = tap % 3;
        const float* swp = &sw[(icl * 9 + tap) * 36 + ty * 8];
        float4 w0 = *(const float4*)(swp);
        float4 w1 = *(const float4*)(swp + 4);
        float wv[8] = {w0.x, w0.y, w0.z, w0.w, w1.x, w1.y, w1.z, w1.w};
#pragma unroll
        for (int j = 0; j < 8; ++j)
#pragma unroll
          for (int q = 0; q < 4; ++q)
            acc[j][q] = fmaf(r[dy][q + kx], wv[j], acc[j][q]);
      }
    }
  }

#pragma unroll
  for (int j = 0; j < 8; ++j) {
    int oc = ocb + ty * 8 + j;
    float b = bias[oc];
#pragma unroll
    for (int q = 0; q < 4; ++q) {
      float v = acc[j][q] + b;
      out[(size_t)oc * 6400 + p0 + q] = fmaxf(v, 0.f);
    }
  }
}

// ---------------------------------------------------------------------------
// Kernel 2: 1x1 convs (RPN cls 18ch + bbox 36ch), K=512.
// grid 100, block (64,4). ty covers 16 output slots (o = ty*16+j, o<54 valid).
// ---------------------------------------------------------------------------
__global__ __launch_bounds__(256) void k_rpn(const float* __restrict__ h,
                                             const float* __restrict__ cls_w,
                                             const float* __restrict__ cls_b,
                                             const float* __restrict__ bbox_w,
                                             const float* __restrict__ bbox_b,
                                             float* __restrict__ cls_out,
                                             float* __restrict__ bbox_out) {
  __shared__ float swt[64 * 56 + 16];
  const int tx = threadIdx.x, ty = threadIdx.y;
  const int tid = ty * 64 + tx;
  const int px = blockIdx.x * 64 + tx;

  float acc[16];
#pragma unroll
  for (int j = 0; j < 16; ++j) acc[j] = 0.f;

  for (int cb = 0; cb < 512; cb += 64) {
    __syncthreads();
    for (int k = tid; k < 64 * 54; k += 256) {
      int o = k / 64, cl = k % 64;
      swt[cl * 56 + o] = (o < 18) ? cls_w[o * 512 + cb + cl]
                                  : bbox_w[(o - 18) * 512 + cb + cl];
    }
    __syncthreads();
    for (int cl = 0; cl < 64; ++cl) {
      float hv = h[(size_t)(cb + cl) * 6400 + px];
      const float* wp = swt + cl * 56 + ty * 16;
      float4 w0 = *(const float4*)(wp);
      float4 w1 = *(const float4*)(wp + 4);
      float4 w2 = *(const float4*)(wp + 8);
      float4 w3 = *(const float4*)(wp + 12);
      acc[0]  = fmaf(hv, w0.x, acc[0]);  acc[1]  = fmaf(hv, w0.y, acc[1]);
      acc[2]  = fmaf(hv, w0.z, acc[2]);  acc[3]  = fmaf(hv, w0.w, acc[3]);
      acc[4]  = fmaf(hv, w1.x, acc[4]);  acc[5]  = fmaf(hv, w1.y, acc[5]);
      acc[6]  = fmaf(hv, w1.z, acc[6]);  acc[7]  = fmaf(hv, w1.w, acc[7]);
      acc[8]  = fmaf(hv, w2.x, acc[8]);  acc[9]  = fmaf(hv, w2.y, acc[9]);
      acc[10] = fmaf(hv, w2.z, acc[10]); acc[11] = fmaf(hv, w2.w, acc[11]);
      acc[12] = fmaf(hv, w3.x, acc[12]); acc[13] = fmaf(hv, w3.y, acc[13]);
      acc[14] = fmaf(hv, w3.z, acc[14]); acc[15] = fmaf(hv, w3.w, acc[15]);
    }
  }
#pragma unroll
  for (int j = 0; j < 16; ++j) {
    int o = ty * 16 + j;
    if (o < 54) {
      float v = acc[j] + ((o < 18) ? cls_b[o] : bbox_b[o - 18]);
      if (o < 18) cls_out[(size_t)o * 6400 + px] = v;
      else        bbox_out[(size_t)(o - 18) * 6400 + px] = v;
    }
  }
}

// ---------------------------------------------------------------------------
// Kernel T: transpose base_feat [1024][6400] -> ft [6400][1024]
// ---------------------------------------------------------------------------
__global__ __launch_bounds__(256) void k_transpose(const float* __restrict__ in,
                                                   float* __restrict__ outp) {
  __shared__ float tile[64][65];
  const int tx = threadIdx.x, ty = threadIdx.y;
  const int cb = blockIdx.x * 64, pb = blockIdx.y * 64;
  for (int rr = ty; rr < 64; rr += 4)
    tile[rr][tx] = in[(size_t)(cb + rr) * 6400 + pb + tx];
  __syncthreads();
  for (int rr = ty; rr < 64; rr += 4)
    outp[(size_t)(pb + rr) * 1024 + cb + tx] = tile[tx][rr];
}

// ---------------------------------------------------------------------------
// Kernel 3: scores (2-class softmax), box decode+clip, sort keys, histogram.
// ---------------------------------------------------------------------------
__global__ __launch_bounds__(256) void k_score(const float* __restrict__ cls,
                                               const float* __restrict__ bbx,
                                               const float* __restrict__ im_info,
                                               float4* __restrict__ boxes,
                                               unsigned long long* __restrict__ keys,
                                               unsigned int* __restrict__ hist) {
  const int i = blockIdx.x * 256 + threadIdx.x;
  if (i >= 57600) return;
  const int p = i / 9, a = i % 9;
  const int yy = p / 100, xx = p % 100;

  // anchors (base=16, ratios .5/1/2, scales 8/16/32) -- precomputed exactly
  const float anc[9][4] = {
    {-84.f,-40.f,99.f,55.f},   {-176.f,-88.f,191.f,103.f}, {-360.f,-184.f,375.f,199.f},
    {-56.f,-56.f,71.f,71.f},   {-120.f,-120.f,135.f,135.f},{-248.f,-248.f,263.f,263.f},
    {-36.f,-80.f,51.f,95.f},   {-80.f,-168.f,95.f,183.f},  {-168.f,-344.f,183.f,359.f}};

  float l0 = cls[(size_t)a * 6400 + p];
  float l1 = cls[(size_t)(9 + a) * 6400 + p];
  float mx = fmaxf(l0, l1);
  float e0 = expf(l0 - mx), e1 = expf(l1 - mx);
  float sc = e1 / (e0 + e1);

  float d0 = bbx[(size_t)(4 * a + 0) * 6400 + p];
  float d1 = bbx[(size_t)(4 * a + 1) * 6400 + p];
  float d2 = bbx[(size_t)(4 * a + 2) * 6400 + p];
  float d3 = bbx[(size_t)(4 * a + 3) * 6400 + p];

  float ax1 = anc[a][0] + xx * 16.f, ay1 = anc[a][1] + yy * 16.f;
  float ax2 = anc[a][2] + xx * 16.f, ay2 = anc[a][3] + yy * 16.f;
  float w = ax2 - ax1 + 1.f, hh = ay2 - ay1 + 1.f;
  float cx = ax1 + 0.5f * w, cy = ay1 + 0.5f * hh;
  float pcx = d0 * w + cx, pcy = d1 * hh + cy;
  float pw = expf(d2) * w, ph = expf(d3) * hh;
  float bx1 = pcx - 0.5f * pw, by1 = pcy - 0.5f * ph;
  float bx2 = pcx + 0.5f * pw, by2 = pcy + 0.5f * ph;

  float imh = im_info[0], imw = im_info[1];
  bx1 = fminf(fmaxf(bx1, 0.f), imw - 1.f);
  by1 = fminf(fmaxf(by1, 0.f), imh - 1.f);
  bx2 = fminf(fmaxf(bx2, 0.f), imw - 1.f);
  by2 = fminf(fmaxf(by2, 0.f), imh - 1.f);

  boxes[i] = make_float4(bx1, by1, bx2, by2);
  unsigned sb = __float_as_uint(sc);  // score in (0,1): positive -> monotonic bits
  keys[i] = ((unsigned long long)sb << 32) | (unsigned long long)(0xFFFFFFFFu - (unsigned)i);
  atomicAdd(&hist[sb >> 16], 1u);
}

// ---------------------------------------------------------------------------
// Kernel 4: find cutoff bin b* = max{b : count(bin >= b) >= 6000}
// ---------------------------------------------------------------------------
__global__ __launch_bounds__(256) void k_cutoff(const unsigned int* __restrict__ hist,
                                                unsigned int* __restrict__ meta) {
  __shared__ unsigned csum[256];
  __shared__ unsigned sbin[256];
  __shared__ int schunk;
  __shared__ unsigned sacc;
  const int t = threadIdx.x;
  unsigned s = 0;
  for (int b = 0; b < 256; ++b) s += hist[t * 256 + b];
  csum[t] = s;
  __syncthreads();
  if (t == 0) {
    unsigned acc = 0; int tc = 0;
    for (int c = 255; c >= 0; --c) {
      if (acc + csum[c] >= 6000u) { tc = c; break; }
      acc += csum[c];
    }
    schunk = tc; sacc = acc;
  }
  __syncthreads();
  const int tc = schunk;
  sbin[t] = hist[tc * 256 + t];
  __syncthreads();
  if (t == 0) {
    unsigned acc = sacc; int bstar = tc * 256;
    for (int b = 255; b >= 0; --b) {
      acc += sbin[b];
      if (acc >= 6000u) { bstar = tc * 256 + b; break; }
    }
    meta[0] = (unsigned)bstar;
  }
}

// ---------------------------------------------------------------------------
// Kernel 4c: compact candidate indices (bin >= b*)
// ---------------------------------------------------------------------------
__global__ __launch_bounds__(256) void k_compact(const unsigned long long* __restrict__ keys,
                                                 unsigned int* __restrict__ meta,
                                                 int* __restrict__ cand) {
  const int i = blockIdx.x * 256 + threadIdx.x;
  if (i >= 57600) return;
  unsigned bin = (unsigned)(keys[i] >> 48);
  if (bin >= meta[0]) {
    unsigned pos = atomicAdd(&meta[1], 1u);
    cand[pos] = i;
  }
}

// ---------------------------------------------------------------------------
// Kernel 5a: exact rank of each candidate = #keys strictly greater.
// grid (225, 8): x over candidate slots, y over key-space splits of 7200.
// ---------------------------------------------------------------------------
__global__ __launch_bounds__(256) void k_rank(const unsigned long long* __restrict__ keys,
                                              const unsigned int* __restrict__ meta,
                                              const int* __restrict__ cand,
                                              int* __restrict__ rnk) {
  __shared__ unsigned long long sk[256];
  const int nc = (int)meta[1];
  if (blockIdx.x * 256 >= nc) return;
  const int cs = blockIdx.x * 256 + threadIdx.x;
  const bool act = cs < nc;
  const unsigned long long mk = act ? keys[cand[cs]] : ~0ull;
  int cnt = 0;
  const int base = blockIdx.y * 7200;
  for (int cb = 0; cb < 7200; cb += 256) {
    sk[threadIdx.x] = (cb + threadIdx.x < 7200) ? keys[base + cb + threadIdx.x] : 0ull;
    __syncthreads();
    if (act) {
#pragma unroll 8
      for (int j = 0; j < 256; ++j) cnt += (sk[j] > mk) ? 1 : 0;
    }
    __syncthreads();
  }
  if (act && cnt) atomicAdd(&rnk[cs], cnt);
}

// ---------------------------------------------------------------------------
// Kernel 5b: scatter top-6000 boxes into rank order.
// ---------------------------------------------------------------------------
__global__ __launch_bounds__(256) void k_scatter(const float4* __restrict__ boxes,
                                                 const unsigned int* __restrict__ meta,
                                                 const int* __restrict__ cand,
                                                 const int* __restrict__ rnk,
                                                 float4* __restrict__ btop) {
  const int cs = blockIdx.x * 256 + threadIdx.x;
  if (cs < (int)meta[1]) {
    int r = rnk[cs];
    if (r < 6000) btop[r] = boxes[cand[cs]];
  }
}

// ---------------------------------------------------------------------------
// Kernel 6: NMS suppression bitmask. grid (94, 1500), block (64,4).
// wave (i, w): bit j=w*64+lane set iff j>i and IoU(box_i,box_j)>0.7
// ---------------------------------------------------------------------------
__global__ __launch_bounds__(256) void k_mask(const float4* __restrict__ btop,
                                              unsigned long long* __restrict__ mask) {
  const int lane = threadIdx.x;
  const int i = blockIdx.y * 4 + threadIdx.y;
  const int w = blockIdx.x;
  const int j = w * 64 + lane;
  float4 bi = btop[i];
  float4 bj = (j < 6000) ? btop[j] : make_float4(0.f, 0.f, 0.f, 0.f);
  float ai = (bi.z - bi.x + 1.f) * (bi.w - bi.y + 1.f);
  float aj = (bj.z - bj.x + 1.f) * (bj.w - bj.y + 1.f);
  float xx1 = fmaxf(bi.x, bj.x), yy1 = fmaxf(bi.y, bj.y);
  float xx2 = fminf(bi.z, bj.z), yy2 = fminf(bi.w, bj.w);
  float inter = fmaxf(xx2 - xx1 + 1.f, 0.f) * fmaxf(yy2 - yy1 + 1.f, 0.f);
  float iou = inter / (ai + aj - inter);
  bool sup = (j < 6000) && (j > i) && (iou > 0.7f);
  unsigned long long bal = __ballot(sup);
  if (lane == 0) mask[(size_t)i * 94 + w] = bal;
}

// ---------------------------------------------------------------------------
// Kernel 7: sequential NMS scan, single wave. Distributed 94-word suppression
// bitset (lane L owns words L and 64+L), depth-8 row prefetch, early exit at
// 300 keeps. Writes rois (out[0..1500)) and roib.
// ---------------------------------------------------------------------------
__global__ __launch_bounds__(64) void k_nms_scan(const unsigned long long* __restrict__ mask,
                                                 const float4* __restrict__ btop,
                                                 float4* __restrict__ roib,
                                                 float* __restrict__ rois) {
  const int lane = threadIdx.x;
  for (int k = lane; k < 1500; k += 64) rois[k] = 0.f;
  {
    float4 z = make_float4(0.f, 0.f, 0.f, 0.f);
    for (int k = lane; k < 300; k += 64) roib[k] = z;
  }
  unsigned long long sLo = 0ull, sHi = 0ull;
  unsigned long long pLo[8], pHi[8];
  float4 pBx[8];
#pragma unroll
  for (int u = 0; u < 8; ++u) {
    pLo[u] = mask[(size_t)u * 94 + lane];
    pHi[u] = (lane < 30) ? mask[(size_t)u * 94 + 64 + lane] : 0ull;
    pBx[u] = btop[u];
  }
  int kc = 0;
  for (int base = 0; base < 6000; base += 8) {
#pragma unroll
    for (int u = 0; u < 8; ++u) {
      const int i = base + u;
      unsigned long long rowLo = pLo[u], rowHi = pHi[u];
      float4 bx = pBx[u];
      const int ip = i + 8;
      if (ip < 6000) {
        pLo[u] = mask[(size_t)ip * 94 + lane];
        pHi[u] = (lane < 30) ? mask[(size_t)ip * 94 + 64 + lane] : 0ull;
        pBx[u] = btop[ip];
      }
      const int w = i >> 6, b = i & 63;
      unsigned long long cw = (w < 64) ? __shfl(sLo, w, 64) : __shfl(sHi, w - 64, 64);
      if (!((cw >> b) & 1ull)) {
        if (lane == 0) {
          rois[kc * 5 + 1] = bx.x; rois[kc * 5 + 2] = bx.y;
          rois[kc * 5 + 3] = bx.z; rois[kc * 5 + 4] = bx.w;
          roib[kc] = bx;
        }
        sLo |= rowLo;
        if (lane < 30) sHi |= rowHi;
        ++kc;
        if (kc >= 300) return;
      }
    }
  }
}

// ---------------------------------------------------------------------------
// Kernel 8: fused ROI-align (7x7, 2x2 samples) + spatial mean -> vec[300][1024]
// Reads transposed feature ft[(y*100+x)*1024 + c]; one block per roi,
// thread owns 4 channels (float4 per corner, coalesced).
// ---------------------------------------------------------------------------
__global__ __launch_bounds__(256) void k_roialign(const float* __restrict__ ft,
                                                  const float4* __restrict__ roib,
                                                  float* __restrict__ vec) {
  const int r = blockIdx.x;
  const int tid = threadIdx.x;
  __shared__ int sx0[14], sx1[14], sy0[14], sy1[14];
  __shared__ float slx[14], sly[14];

  float4 bx = roib[r];
  float x1 = bx.x * 0.0625f, y1 = bx.y * 0.0625f;
  float x2 = bx.z * 0.0625f, y2 = bx.w * 0.0625f;
  float bw = fmaxf(x2 - x1, 1.0f) / 7.0f;
  float bh = fmaxf(y2 - y1, 1.0f) / 7.0f;
  if (tid < 14) {
    float off = ((float)tid + 0.5f) / 2.0f;
    float xs = fminf(fmaxf(x1 + off * bw, 0.f), 99.f);
    float x0f = floorf(xs);
    sx0[tid] = (int)x0f;
    sx1[tid] = min((int)x0f + 1, 99);
    slx[tid] = xs - x0f;
  } else if (tid < 28) {
    int t = tid - 14;
    float off = ((float)t + 0.5f) / 2.0f;
    float ys = fminf(fmaxf(y1 + off * bh, 0.f), 63.f);
    float y0f = floorf(ys);
    sy0[t] = (int)y0f;
    sy1[t] = min((int)y0f + 1, 63);
    sly[t] = ys - y0f;
  }
  __syncthreads();

  float ax = 0.f, ay = 0.f, az = 0.f, aw = 0.f;
  for (int py = 0; py < 7; ++py) {
    for (int px = 0; px < 7; ++px) {
      float cx_ = 0.f, cy_ = 0.f, cz_ = 0.f, cw_ = 0.f;
#pragma unroll
      for (int ss = 0; ss < 2; ++ss) {
        const int s = py * 2 + ss;
        const int yA = sy0[s], yB = sy1[s];
        const float ly = sly[s];
#pragma unroll
        for (int tt = 0; tt < 2; ++tt) {
          const int t = px * 2 + tt;
          const int xA = sx0[t], xB = sx1[t];
          const float lx = slx[t];
          const float w00 = (1.f - ly) * (1.f - lx), w01 = (1.f - ly) * lx;
          const float w10 = ly * (1.f - lx),         w11 = ly * lx;
          const float4 v00 = *(const float4*)(ft + ((size_t)(yA * 100 + xA) << 10) + (tid << 2));
          const float4 v01 = *(const float4*)(ft + ((size_t)(yA * 100 + xB) << 10) + (tid << 2));
          const float4 v10 = *(const float4*)(ft + ((size_t)(yB * 100 + xA) << 10) + (tid << 2));
          const float4 v11 = *(const float4*)(ft + ((size_t)(yB * 100 + xB) << 10) + (tid << 2));
          cx_ += v00.x * w00 + v01.x * w01 + v10.x * w10 + v11.x * w11;
          cy_ += v00.y * w00 + v01.y * w01 + v10.y * w10 + v11.y * w11;
          cz_ += v00.z * w00 + v01.z * w01 + v10.z * w10 + v11.z * w11;
          cw_ += v00.w * w00 + v01.w * w01 + v10.w * w10 + v11.w * w11;
        }
      }
      ax += cx_ * 0.25f; ay += cy_ * 0.25f; az += cz_ * 0.25f; aw += cw_ * 0.25f;
    }
  }
  float4 o;
  o.x = ax / 49.0f; o.y = ay / 49.0f; o.z = az / 49.0f; o.w = aw / 49.0f;
  *(float4*)(vec + (size_t)r * 1024 + (tid << 2)) = o;
}

// ---------------------------------------------------------------------------
// Kernel 9a: hidden = relu(vec @ fc_w + fc_b).  M=300, K=1024, N=2048.
// grid (8, 25), block (64,4); M-tile 12 staged in LDS (49,152 B).
// ---------------------------------------------------------------------------
__global__ __launch_bounds__(256) void k_fc1(const float* __restrict__ vec,
                                             const float* __restrict__ fw,
                                             const float* __restrict__ fb,
                                             float* __restrict__ hidden) {
  __shared__ float sa[12][1024];
  const int tx = threadIdx.x, ty = threadIdx.y;
  const int tid = ty * 64 + tx;
  const int nb = blockIdx.x * 256, mb = blockIdx.y * 12;

  for (int mm = 0; mm < 12; ++mm) {
    int m = mb + mm;
    float4 v = (m < 300) ? ((const float4*)(vec + (size_t)m * 1024))[tid]
                         : make_float4(0.f, 0.f, 0.f, 0.f);
    ((float4*)sa[mm])[tid] = v;
  }
  __syncthreads();

  const int n = nb + tx * 4;
  float acc[3][4];
#pragma unroll
  for (int mi = 0; mi < 3; ++mi)
#pragma unroll
    for (int q = 0; q < 4; ++q) acc[mi][q] = 0.f;

  for (int k = 0; k < 1024; ++k) {
    float4 b4 = *(const float4*)(fw + (size_t)k * 2048 + n);
#pragma unroll
    for (int mi = 0; mi < 3; ++mi) {
      float a = sa[ty * 3 + mi][k];
      acc[mi][0] = fmaf(a, b4.x, acc[mi][0]);
      acc[mi][1] = fmaf(a, b4.y, acc[mi][1]);
      acc[mi][2] = fmaf(a, b4.z, acc[mi][2]);
      acc[mi][3] = fmaf(a, b4.w, acc[mi][3]);
    }
  }
  float4 bias = *(const float4*)(fb + n);
#pragma unroll
  for (int mi = 0; mi < 3; ++mi) {
    int m = mb + ty * 3 + mi;
    if (m < 300) {
      float4 o;
      o.x = fmaxf(acc[mi][0] + bias.x, 0.f);
      o.y = fmaxf(acc[mi][1] + bias.y, 0.f);
      o.z = fmaxf(acc[mi][2] + bias.z, 0.f);
      o.w = fmaxf(acc[mi][3] + bias.w, 0.f);
      *(float4*)(hidden + (size_t)m * 2048 + n) = o;
    }
  }
}

// ---------------------------------------------------------------------------
// Kernel 9b: cls_prob (softmax-21) and bbox_pred (84) per roi row.
// ---------------------------------------------------------------------------
__global__ __launch_bounds__(128) void k_head(const float* __restrict__ hidden,
                                              const float* __restrict__ cw,
                                              const float* __restrict__ cbias,
                                              const float* __restrict__ bw,
                                              const float* __restrict__ bbias,
                                              float* __restrict__ out_cls,
                                              float* __restrict__ out_bbox) {
  const int m = blockIdx.x, tid = threadIdx.x;
  __shared__ float sh[2048];
  __shared__ float slog[32];
  __shared__ float sred[2];
  for (int k = tid; k < 512; k += 128)
    ((float4*)sh)[k] = ((const float4*)(hidden + (size_t)m * 2048))[k];
  __syncthreads();
  if (tid < 21) {
    float a = 0.f;
#pragma unroll 4
    for (int k = 0; k < 2048; ++k) a = fmaf(sh[k], cw[(size_t)k * 21 + tid], a);
    slog[tid] = a + cbias[tid];
  } else if (tid < 105) {
    int j = tid - 21;
    float a = 0.f;
#pragma unroll 4
    for (int k = 0; k < 2048; ++k) a = fmaf(sh[k], bw[(size_t)k * 84 + j], a);
    out_bbox[(size_t)m * 84 + j] = a + bbias[j];
  }
  __syncthreads();
  if (tid == 0) {
    float mx = slog[0];
    for (int o = 1; o < 21; ++o) mx = fmaxf(mx, slog[o]);
    float sm = 0.f;
    for (int o = 0; o < 21; ++o) sm += expf(slog[o] - mx);
    sred[0] = mx; sred[1] = sm;
  }
  __syncthreads();
  if (tid < 21) out_cls[(size_t)m * 21 + tid] = expf(slog[tid] - sred[0]) / sred[1];
}

// ---------------------------------------------------------------------------
extern "C" void kernel_launch(void* const* d_in, const int* in_sizes, int n_in,
                              void* d_out, int out_size, void* d_ws, size_t ws_size,
                              hipStream_t stream) {
  const float* base_feat  = (const float*)d_in[0];
  const float* im_info    = (const float*)d_in[1];
  const float* rpn_conv_w = (const float*)d_in[2];
  const float* rpn_conv_b = (const float*)d_in[3];
  const float* rpn_cls_w  = (const float*)d_in[4];
  const float* rpn_cls_b  = (const float*)d_in[5];
  const float* rpn_bbox_w = (const float*)d_in[6];
  const float* rpn_bbox_b = (const float*)d_in[7];
  const float* fc_w   = (const float*)d_in[8];
  const float* fc_b   = (const float*)d_in[9];
  const float* cls_w  = (const float*)d_in[10];
  const float* cls_b  = (const float*)d_in[11];
  const float* bbox_w = (const float*)d_in[12];
  const float* bbox_b = (const float*)d_in[13];

  char* ws = (char*)d_ws;
  float* h     = (float*)(ws);               // [512][6400]
  float* ft    = (float*)(ws);               // [6400][1024] (overlays h, after k_rpn)
  float* clsL  = (float*)(ws + OFF_CLS);
  float* bboxL = (float*)(ws + OFF_BBOX);
  float4* boxes4 = (float4*)(ws + OFF_BOXES);
  unsigned long long* keys = (unsigned long long*)(ws + OFF_KEYS);
  unsigned int* hist = (unsigned int*)(ws + OFF_HIST);
  unsigned int* meta = (unsigned int*)(ws + OFF_META);
  int* rnk  = (int*)(ws + OFF_RNK);
  int* cand = (int*)(ws + OFF_CAND);
  float4* btop4 = (float4*)(ws + OFF_BTOP);
  unsigned long long* mask = (unsigned long long*)(ws + OFF_MASK);
  float4* roib4 = (float4*)(ws + OFF_ROIB);
  float* vec    = (float*)(ws + OFF_VEC);
  float* hidden = (float*)(ws + OFF_HID);

  float* out = (float*)d_out;   // rois [0,1500) | cls_prob [1500,7800) | bbox [7800,33000)

  // zero hist + meta + rnk (contiguous 492,800 B) -- required every launch
  hipMemsetAsync(ws + OFF_HIST, 0, 262144u + 256u + 230400u, stream);

  k_conv<<<dim3(25, 16), dim3(64, 4), 0, stream>>>(base_feat, rpn_conv_w, rpn_conv_b, h);
  k_rpn<<<dim3(100), dim3(64, 4), 0, stream>>>(h, rpn_cls_w, rpn_cls_b, rpn_bbox_w, rpn_bbox_b,
                                               clsL, bboxL);
  k_transpose<<<dim3(16, 100), dim3(64, 4), 0, stream>>>(base_feat, ft);  // after k_rpn (overlays h)
  k_score<<<dim3(225), dim3(256), 0, stream>>>(clsL, bboxL, im_info, boxes4, keys, hist);
  k_cutoff<<<dim3(1), dim3(256), 0, stream>>>(hist, meta);
  k_compact<<<dim3(225), dim3(256), 0, stream>>>(keys, meta, cand);
  k_rank<<<dim3(225, 8), dim3(256), 0, stream>>>(keys, meta, cand, rnk);
  k_scatter<<<dim3(225), dim3(256), 0, stream>>>(boxes4, meta, cand, rnk, btop4);
  k_mask<<<dim3(94, 1500), dim3(64, 4), 0, stream>>>(btop4, mask);
  k_nms_scan<<<dim3(1), dim3(64), 0, stream>>>(mask, btop4, roib4, out);
  k_roialign<<<dim3(300), dim3(256), 0, stream>>>(ft, roib4, vec);
  k_fc1<<<dim3(8, 25), dim3(64, 4), 0, stream>>>(vec, fc_w, fc_b, hidden);
  k_head<<<dim3(300), dim3(128), 0, stream>>>(hidden, cls_w, cls_b, bbox_w, bbox_b,
                                              out + 1500, out + 7800);
}